// Round 14
// baseline (187.098 us; speedup 1.0000x reference)
//
#include <hip/hip_runtime.h>
#include <hip/hip_bf16.h>
#include <math.h>

#define B_ROWS 8192
#define D_DIM  128
#define TILE   128
#define NT     (B_ROWS / TILE)          // 64
#define NPAIRS (NT * (NT + 1) / 2)      // 2080
#define MAXP   (1 << 18)                // 256K slots; expected ~42K positive pairs

typedef __attribute__((ext_vector_type(8))) short bf16x8;
typedef __attribute__((ext_vector_type(4))) float f32x4;

// Convert fp32 E -> bf16 Hi (RN). Also zero-inits sums/cnts/pcnt and out.
// bf16-only sim is safe: all sigmoid args are >=30 from 0 (sigma' <= e^-30),
// and positive dots are recomputed exactly in fp32 in pairs_kernel.
__global__ __launch_bounds__(256)
void convert_kernel(const float* __restrict__ emb, ushort* __restrict__ hi,
                    unsigned* __restrict__ zero_region, float* __restrict__ out)
{
    const int idx = blockIdx.x * 256 + threadIdx.x;   // 262144 float4 segments
    const float4 v = ((const float4*)emb)[idx];
    const float a[4] = {v.x, v.y, v.z, v.w};
    ushort h[4];
#pragma unroll
    for (int i = 0; i < 4; ++i) {
        const unsigned u = __float_as_uint(a[i]);
        h[i] = (ushort)((u + 0x7FFFu + ((u >> 16) & 1u)) >> 16);   // RN to bf16
    }
    *(ushort4*)(hi + (size_t)idx * 4) = make_ushort4(h[0], h[1], h[2], h[3]);
    if (idx < 16448) zero_region[idx] = 0u;   // sums+cnts+pcnt (65792 B)
    if (idx == 0) *out = 0.f;
}

// Pass 1: masked partial row/col-max of sim over negatives via bf16 MFMA.
// NO GLOBAL ATOMICS: block (it,jt) is the unique producer of
//   part[jt][i0..i0+127] (row direction) and part[it][j0..j0+127] (col dir),
// so partials are written with plain coalesced stores (every cell of
// part[64][8192] is written exactly once; no init needed).
__global__ __launch_bounds__(256)
void maxneg_mfma(const ushort* __restrict__ Hi,
                 const int* __restrict__ lab, float* __restrict__ part,
                 int* __restrict__ pcnt, int* __restrict__ pi, int* __restrict__ pj)
{
    __shared__ ushort TA[TILE * D_DIM];   // 32 KB
    __shared__ ushort TB[TILE * D_DIM];   // 32 KB
    __shared__ float rowpart[2][TILE];    // [wc][row] cross-wave merge
    __shared__ float colpart[2][TILE];    // [wr][col]
    __shared__ int Li[TILE], Lj[TILE];

    const int kpair = blockIdx.x;
    int it = (int)((2.0 * NT + 1.0 - sqrt((2.0 * NT + 1.0) * (2.0 * NT + 1.0) - 8.0 * kpair)) * 0.5);
    while ((it + 1) * NT - ((it + 1) * it) / 2 <= kpair) ++it;
    while (it * NT - (it * (it - 1)) / 2 > kpair) --it;
    const int jt = it + (kpair - (it * NT - (it * (it - 1)) / 2));
    const int i0 = it * TILE, j0 = jt * TILE;

    const int tid = threadIdx.x;
    const int w = tid >> 6, lane = tid & 63;

    // Stage: waves 0,1 -> TA halves; waves 2,3 -> TB halves. Each instr moves
    // 1 KB (4 rows); LDS dest linear (wave base + lane*16); global src chunk
    // pre-swizzled: LDS[row][c] = global[row][c ^ (row&7)].
    {
        const ushort* gb = Hi + (size_t)((w >= 2) ? j0 : i0) * D_DIM;
        ushort* lb = (w >= 2) ? TB : TA;
        const int rbase = (w & 1) * 64;
#pragma unroll
        for (int sub = 0; sub < 16; ++sub) {
            const int r = rbase + sub * 4 + (lane >> 4);
            const ushort* s = gb + (size_t)r * D_DIM + (((lane & 15) ^ (r & 7)) << 3);
            __builtin_amdgcn_global_load_lds(
                (const __attribute__((address_space(1))) void*)s,
                (__attribute__((address_space(3))) void*)(lb + (rbase + sub * 4) * D_DIM),
                16, 0, 0);
        }
    }
    if (tid < TILE) Li[tid] = lab[i0 + tid];
    else            Lj[tid & (TILE - 1)] = lab[j0 + (tid & (TILE - 1))];
    __syncthreads();   // drains vmcnt (global_load_lds) + lgkmcnt

    const int wr = w >> 1, wc = w & 1;
    const int lr = lane & 15, lk = lane >> 4;
    const int sx = lr & 7;    // row&7 for all fragment rows (row offsets mult of 8)

    f32x4 acc[4][4];
#pragma unroll
    for (int m = 0; m < 4; ++m)
#pragma unroll
        for (int n = 0; n < 4; ++n) acc[m][n] = (f32x4){0.f, 0.f, 0.f, 0.f};

#pragma unroll
    for (int ks = 0; ks < 4; ++ks) {
        const int ch = (((ks * 4 + lk) ^ sx) << 3);   // swizzled chunk offset (ushorts)
        bf16x8 aH[4], bH[4];
#pragma unroll
        for (int m = 0; m < 4; ++m)
            aH[m] = *(const bf16x8*)&TA[(wr * 64 + m * 16 + lr) * D_DIM + ch];
#pragma unroll
        for (int n = 0; n < 4; ++n)
            bH[n] = *(const bf16x8*)&TB[(wc * 64 + n * 16 + lr) * D_DIM + ch];
#pragma unroll
        for (int m = 0; m < 4; ++m)
#pragma unroll
            for (int n = 0; n < 4; ++n)
                acc[m][n] = __builtin_amdgcn_mfma_f32_16x16x32_bf16(aH[m], bH[n], acc[m][n], 0, 0, 0);
    }

    // Epilogue. C/D layout: col = lane&15, row = (lane>>4)*4 + reg.
    const bool diag = (it == jt);
    int ljv[4];
#pragma unroll
    for (int n = 0; n < 4; ++n) ljv[n] = Lj[wc * 64 + n * 16 + lr];

    float colmax[4] = {-INFINITY, -INFINITY, -INFINITY, -INFINITY};
    float rowmax[4][4];
#pragma unroll
    for (int m = 0; m < 4; ++m)
#pragma unroll
        for (int v = 0; v < 4; ++v) rowmax[m][v] = -INFINITY;

    unsigned long long posmask = 0ull;   // bit = m*16 + n*4 + v
#pragma unroll
    for (int m = 0; m < 4; ++m) {
        int liv[4];
#pragma unroll
        for (int v = 0; v < 4; ++v) liv[v] = Li[wr * 64 + m * 16 + lk * 4 + v];
#pragma unroll
        for (int n = 0; n < 4; ++n)
#pragma unroll
            for (int v = 0; v < 4; ++v) {
                const float sv = acc[m][n][v];
                if (liv[v] != ljv[n]) {
                    rowmax[m][v] = fmaxf(rowmax[m][v], sv);
                    colmax[n]    = fmaxf(colmax[n], sv);
                } else {
                    const int gi = i0 + wr * 64 + m * 16 + lk * 4 + v;
                    const int gj = j0 + wc * 64 + n * 16 + lr;
                    if (!diag || gi <= gj)
                        posmask |= (1ull << (m * 16 + n * 4 + v));
                }
            }
    }

    // Wave-aggregated pair append: 1 atomic per wave (pcnt only).
    {
        const int cnt = __popcll(posmask);
        int pre = cnt;
#pragma unroll
        for (int d = 1; d < 64; d <<= 1) {
            const int t = __shfl_up(pre, d, 64);
            if (lane >= d) pre += t;
        }
        int b0 = 0;
        if (lane == 63) b0 = atomicAdd(pcnt, pre);   // pre@63 == wave total
        const int base = __shfl(b0, 63, 64);
        int slot = base + pre - cnt;                 // exclusive prefix
        unsigned long long m2 = posmask;
        while (m2) {
            const int b = __ffsll((long long)m2) - 1;
            m2 &= (m2 - 1);
            const int m = b >> 4, n = (b >> 2) & 3, v = b & 3;
            if (slot < MAXP) {
                pi[slot] = i0 + wr * 64 + m * 16 + lk * 4 + v;
                pj[slot] = j0 + wc * 64 + n * 16 + lr;
            }
            ++slot;
        }
    }

    // row-max: reduce across lr (lanes sharing lk): xor 1,2,4,8
#pragma unroll
    for (int d = 1; d <= 8; d <<= 1)
#pragma unroll
        for (int m = 0; m < 4; ++m)
#pragma unroll
            for (int v = 0; v < 4; ++v)
                rowmax[m][v] = fmaxf(rowmax[m][v], __shfl_xor(rowmax[m][v], d, 64));
    if (lr == 0) {
#pragma unroll
        for (int m = 0; m < 4; ++m)
#pragma unroll
            for (int v = 0; v < 4; ++v)
                rowpart[wc][wr * 64 + m * 16 + lk * 4 + v] = rowmax[m][v];
    }
    // col-max: reduce across lk (stride-16 lanes): xor 16,32
#pragma unroll
    for (int d = 16; d <= 32; d <<= 1)
#pragma unroll
        for (int n = 0; n < 4; ++n)
            colmax[n] = fmaxf(colmax[n], __shfl_xor(colmax[n], d, 64));
    if (lk == 0) {
#pragma unroll
        for (int n = 0; n < 4; ++n)
            colpart[wr][wc * 64 + n * 16 + lr] = colmax[n];
    }
    __syncthreads();

    // Cross-wave merge + plain coalesced stores (unique producer per cell).
    if (tid < TILE) {
        part[(size_t)jt * B_ROWS + i0 + tid] = fmaxf(rowpart[0][tid], rowpart[1][tid]);
    } else {
        const int t = tid - TILE;
        part[(size_t)it * B_ROWS + j0 + t] = fmaxf(colpart[0][t], colpart[1][t]);
    }
}

// Fold 64 tile-partials per row into keys[i] (plain float, no encoding).
__global__ __launch_bounds__(256)
void reduce_kernel(const float* __restrict__ part, float* __restrict__ keys)
{
    const int i = blockIdx.x * 256 + threadIdx.x;   // 8192
    float m0 = part[i];
    float m1 = part[B_ROWS + i];
#pragma unroll
    for (int jt = 2; jt < NT; jt += 2) {
        m0 = fmaxf(m0, part[(size_t)jt * B_ROWS + i]);
        m1 = fmaxf(m1, part[(size_t)(jt + 1) * B_ROWS + i]);
    }
    keys[i] = fmaxf(m0, m1);
}

// Pass 2: per positive pair, recompute the dot EXACTLY in fp32, accumulate
// per-row sigmoid sums and counts (both directions for i!=j).
__global__ __launch_bounds__(256)
void pairs_kernel(const float* __restrict__ emb, const int* __restrict__ pcnt,
                  const int* __restrict__ pi, const int* __restrict__ pj,
                  const float* __restrict__ keys,
                  float* __restrict__ sums, unsigned* __restrict__ cnts)
{
    const int idx = blockIdx.x * 256 + threadIdx.x;
    int n = *pcnt; if (n > MAXP) n = MAXP;
    if (idx >= n) return;
    const int i = pi[idx], j = pj[idx];
    const float4* ei = (const float4*)(emb + (size_t)i * D_DIM);
    const float4* ej = (const float4*)(emb + (size_t)j * D_DIM);
    float s = 0.f;
#pragma unroll
    for (int q = 0; q < 32; ++q) {
        const float4 x = ei[q], y = ej[q];
        s += x.x * y.x + x.y * y.y + x.z * y.z + x.w * y.w;
    }
    atomicAdd(&sums[i], 1.f / (1.f + expf(s - keys[i])));
    atomicAdd(&cnts[i], 1u);
    if (j != i) {
        atomicAdd(&sums[j], 1.f / (1.f + expf(s - keys[j])));
        atomicAdd(&cnts[j], 1u);
    }
}

__global__ __launch_bounds__(256)
void final_kernel(const float* __restrict__ sums, const unsigned* __restrict__ cnts,
                  float* __restrict__ out)
{
    const int i = blockIdx.x * 256 + threadIdx.x;   // 8192
    float v = 3.0f * (1.0f - sums[i] / (float)cnts[i]) / (float)B_ROWS;
#pragma unroll
    for (int d = 1; d < 64; d <<= 1) v += __shfl_xor(v, d, 64);
    if ((threadIdx.x & 63) == 0) atomicAdd(out, v);
}

extern "C" void kernel_launch(void* const* d_in, const int* in_sizes, int n_in,
                              void* d_out, int out_size, void* d_ws, size_t ws_size,
                              hipStream_t stream)
{
    const float* emb = (const float*)d_in[0];
    const int*   lab = (const int*)d_in[1];    // int32 (JAX x64 disabled)
    float*       out = (float*)d_out;

    char* ws = (char*)d_ws;
    ushort*   Hi   = (ushort*)(ws);                         // 2 MB
    float*    part = (float*)(ws + (2u << 20));             // 2 MB [64][8192]
    float*    keys = (float*)(ws + (4u << 20));             // 32 KB
    float*    sums = (float*)(ws + (4u << 20) + 32768);     // 32 KB
    unsigned* cnts = (unsigned*)(ws + (4u << 20) + 65536);  // 32 KB
    int*      pcnt = (int*)(ws + (4u << 20) + 98304);       // 256 B pad
    int*      pi   = (int*)(ws + (4u << 20) + 98560);       // 1 MB
    int*      pj   = (int*)(ws + (4u << 20) + 98560 + 4 * MAXP); // 1 MB

    // convert fuses the zero-init of sums/cnts/pcnt (16448 words) + out;
    // keys is fully overwritten by reduce_kernel, part by maxneg_mfma.
    convert_kernel<<<(B_ROWS * D_DIM / 4) / 256, 256, 0, stream>>>(emb, Hi, (unsigned*)sums, out);
    maxneg_mfma<<<NPAIRS, 256, 0, stream>>>(Hi, lab, part, pcnt, pi, pj);
    reduce_kernel<<<B_ROWS / 256, 256, 0, stream>>>(part, keys);
    pairs_kernel<<<MAXP / 256, 256, 0, stream>>>(emb, pcnt, pi, pj, keys, sums, cnts);
    final_kernel<<<B_ROWS / 256, 256, 0, stream>>>(sums, cnts, out);
}